// Round 17
// baseline (86.116 us; speedup 1.0000x reference)
//
#include <hip/hip_runtime.h>

// NonLocal block: B=4, C=256, P=128, H=W=64, N=4096.
// prep -> proj2 (MFMA bf16, outputs Q/K/V in fp8 e4m3) -> attn v9 (fp8 MFMA flash:
// K/V/P all fp8, LDS 40KB -> 3+ blocks/CU, dbuf, exp2 softmax) -> zbn (MFMA, bf16 Z)
// -> bnfin -> out.
// R17: attn was LDS+stall bound at 2 blocks/CU. fp8 halves LDS bytes AND footprint
// (80->40KB). Both MFMA operands packed identically (8 contig k-bytes @ k=lh*8) so
// HW k-permutation cancels (same argument as the working bf16 QK). Q prescaled x16
// (e4m3 normal range), exp2(sacc/16); P ~1.0 normal; den from f32 (exact norm).

#define SCALE_ 0.08838834764831845f    // 1/sqrt(128)
#define QSCALE_ 2.0404384761599213f    // 1/sqrt(128) * log2(e) * 16

typedef __bf16 bf16x8 __attribute__((ext_vector_type(8)));
typedef float f32x4 __attribute__((ext_vector_type(4)));
typedef unsigned short ushort8v __attribute__((ext_vector_type(8)));

__device__ inline unsigned short f2bf(float f) {  // RNE float->bf16
  unsigned int u = __float_as_uint(f);
  u += 0x7fffu + ((u >> 16) & 1u);
  return (unsigned short)(u >> 16);
}
__device__ inline float bflo(unsigned int u) { return __uint_as_float(u << 16); }
__device__ inline float bfhi(unsigned int u) { return __uint_as_float(u & 0xffff0000u); }

// RNE float -> OCP e4m3fn (bias 7, max 448, min normal 2^-6, denorm quantum 2^-9)
__device__ inline unsigned char f2fp8(float f) {
  unsigned u = __float_as_uint(f);
  unsigned sign = (u >> 24) & 0x80u;
  unsigned a = u & 0x7fffffffu;
  if (a >= 0x43E00000u) return (unsigned char)(sign | 0x7Eu);  // clamp 448
  if (a >= 0x3C800000u) {  // >= 2^-6: normal
    unsigned r = a + 0x0007FFFFu + ((a >> 20) & 1u);  // RNE to 3 mantissa bits
    r &= 0xFFF00000u;
    int e8 = (int)((r >> 23) & 0xFFu) - 120;  // -127+7
    unsigned m3 = (r >> 20) & 7u;
    return (unsigned char)(sign | ((unsigned)e8 << 3) | m3);
  }
  float q = __uint_as_float(a) * 512.0f;  // units of 2^-9
  int d = (int)rintf(q);
  if (d >= 8) return (unsigned char)(sign | 0x08u);
  return (unsigned char)(sign | (unsigned)d);
}

// async global->LDS, 16B per lane; LDS dest = wave-uniform base + lane*16 (linear).
__device__ inline void gl16(const void* g, void* l) {
  __builtin_amdgcn_global_load_lds(
      (const __attribute__((address_space(1))) unsigned int*)(g),
      (__attribute__((address_space(3))) unsigned int*)(l), 16, 0, 0);
}

// ---------------- 0) prep: xT[b][n][c] bf16 + Wb[3][128][256] bf16 ----------------
__global__ __launch_bounds__(256) void prep_kernel(
    const float* __restrict__ x,
    const float* __restrict__ Wt, const float* __restrict__ Wp, const float* __restrict__ Wg,
    unsigned short* __restrict__ xT, unsigned short* __restrict__ Wb) {
  const int tid = threadIdx.x;
  const int bx = blockIdx.x, b = blockIdx.y;
  if (bx >= 64) {
    if (b != 0) return;
#pragma unroll
    for (int it = 0; it < 3; ++it) {
      int k = (bx - 64) * 256 + tid + it * 4096;  // 0..12287
      const float* src = (k < 4096 ? Wt : (k < 8192 ? Wp : Wg)) + (size_t)(k & 4095) * 8;
      float4 a = *(const float4*)src, c = *(const float4*)(src + 4);
      ushort8v us;
      us[0] = f2bf(a.x); us[1] = f2bf(a.y); us[2] = f2bf(a.z); us[3] = f2bf(a.w);
      us[4] = f2bf(c.x); us[5] = f2bf(c.y); us[6] = f2bf(c.z); us[7] = f2bf(c.w);
      *(ushort8v*)(Wb + (size_t)k * 8) = us;
    }
    return;
  }
  __shared__ float sT[128 * 68];
  const int w = tid >> 6, l = tid & 63;
  const int n0 = bx * 64;
  for (int half = 0; half < 2; ++half) {
    if (half) __syncthreads();
#pragma unroll
    for (int it = 0; it < 8; ++it) {
      int e = it * 256 + tid;
      int c = e >> 4, n4 = e & 15;
      float4 v = *(const float4*)(x + (size_t)(b * 256 + half * 128 + c) * 4096 + n0 + n4 * 4);
      *(float4*)(sT + c * 68 + n4 * 4) = v;
    }
    __syncthreads();
#pragma unroll
    for (int it = 0; it < 4; ++it) {
      int c8 = it * 4 + w;
      int n = l;
      ushort8v us;
#pragma unroll
      for (int j = 0; j < 8; ++j) us[j] = f2bf(sT[(c8 * 8 + j) * 68 + n]);
      *(ushort8v*)(xT + (size_t)b * 1048576 + (size_t)(n0 + n) * 256 + half * 128 + c8 * 8) = us;
    }
  }
}

// ---------------- 1) proj2: Q,K,Vt via bf16 MFMA; outputs fp8 ----------------
// Q folds QSCALE_ (1/sqrt(P) * log2e * 16); attn uses exp2(sacc/16).
__global__ __launch_bounds__(256, 3) void proj_kernel(
    const unsigned short* __restrict__ xT, const unsigned short* __restrict__ Wb,
    const float* __restrict__ bt, const float* __restrict__ bp, const float* __restrict__ bg,
    unsigned char* __restrict__ Qb8, unsigned char* __restrict__ Kb8,
    unsigned char* __restrict__ Vtb8) {
  __shared__ unsigned short sX[64 * 256];
  __shared__ unsigned short sW[128 * 64];
  const int tid = threadIdx.x;
  const int w = tid >> 6, l = tid & 63;
  const int l15 = l & 15, lh = l >> 4;
  const int n0 = blockIdx.x * 64;
  const int b = blockIdx.y;
  const int sel = blockIdx.z;
  const unsigned short* xTb = xT + (size_t)b * 1048576;
  const unsigned short* Ws = Wb + (size_t)sel * 32768;
#pragma unroll
  for (int it = 0; it < 8; ++it) {
    int row = w * 16 + it * 2 + (l >> 5);
    int s = l & 31;
    int src = (s & 24) | ((s & 7) ^ (row & 7));
    gl16(xTb + (size_t)(n0 + row) * 256 + src * 8, sX + (w * 16 + it * 2) * 256);
  }
  f32x4 acc[2][4];
#pragma unroll
  for (int mt = 0; mt < 2; ++mt)
#pragma unroll
    for (int nt = 0; nt < 4; ++nt) acc[mt][nt] = (f32x4){0.f, 0.f, 0.f, 0.f};

  for (int ko4 = 0; ko4 < 4; ++ko4) {
    __syncthreads();
#pragma unroll
    for (int it = 0; it < 4; ++it) {
      int p = w * 32 + it * 8 + (l >> 3);
      int s = l & 7;
      gl16(Ws + (size_t)p * 256 + ko4 * 64 + ((s ^ (p & 7)) * 8),
           sW + (w * 32 + it * 8) * 64);
    }
    __syncthreads();
#pragma unroll
    for (int ko2 = 0; ko2 < 2; ++ko2) {
      bf16x8 af[2];
#pragma unroll
      for (int mt = 0; mt < 2; ++mt) {
        int p = w * 32 + mt * 16 + l15;
        af[mt] = *(const bf16x8*)(sW + p * 64 + (((ko2 * 4 + lh) ^ (p & 7)) << 3));
      }
#pragma unroll
      for (int nt = 0; nt < 4; ++nt) {
        int n = nt * 16 + l15;
        int ci = ko4 * 8 + ko2 * 4 + lh;
        int slot = (ci & 24) | ((ci & 7) ^ (n & 7));
        bf16x8 bfv = *(const bf16x8*)(sX + n * 256 + (slot << 3));
#pragma unroll
        for (int mt = 0; mt < 2; ++mt)
          acc[mt][nt] = __builtin_amdgcn_mfma_f32_16x16x32_bf16(af[mt], bfv, acc[mt][nt], 0, 0, 0);
      }
    }
  }
  const float* bias = sel == 0 ? bt : (sel == 1 ? bp : bg);
  const float scl = sel == 0 ? QSCALE_ : 1.0f;
#pragma unroll
  for (int mt = 0; mt < 2; ++mt) {
    int pb = w * 32 + mt * 16 + lh * 4;
    float4 bv = *(const float4*)(bias + pb);
    const float* bvf = (const float*)&bv;
    if (sel < 2) {
      unsigned char* dst = (sel == 0 ? Qb8 : Kb8) + (size_t)b * 524288;
#pragma unroll
      for (int nt = 0; nt < 4; ++nt) {
        uchar4 us;
        us.x = f2fp8((acc[mt][nt][0] + bv.x) * scl);
        us.y = f2fp8((acc[mt][nt][1] + bv.y) * scl);
        us.z = f2fp8((acc[mt][nt][2] + bv.z) * scl);
        us.w = f2fp8((acc[mt][nt][3] + bv.w) * scl);
        *(uchar4*)(dst + (size_t)(n0 + nt * 16 + l15) * 128 + pb) = us;
      }
    } else {
      unsigned char* dst = Vtb8 + (size_t)b * 524288;
#pragma unroll
      for (int nt = 0; nt < 4; ++nt)
#pragma unroll
        for (int r = 0; r < 4; ++r)
          dst[(size_t)(pb + r) * 4096 + n0 + nt * 16 + l15] = f2fp8(acc[mt][nt][r] + bvf[r]);
    }
  }
}

// ---------------- 2) attn v9: fp8 K/V/P, KVBLK=64, 32 q/wave, dbuf ----------------
// grid (32 qb, 4 b, 4 split); 256 thr = 4 waves; wave w owns q rows n0+w*32..+31
// as two 16-row sets. LDS 40KB (fp8): K dbuf 2x8K [64m][128d], V dbuf 2x8K
// [128d][64m], sP 4x2K [32q][64m]. All reads 8B; both MFMA operands packed as
// 8 contiguous k-bytes @ k=lh*8 (HW k-permutation cancels).
__global__ __launch_bounds__(256, 3) void attn_kernel(
    const unsigned char* __restrict__ Qb8, const unsigned char* __restrict__ Kb8,
    const unsigned char* __restrict__ Vtb8, unsigned short* __restrict__ Ytp,
    float* __restrict__ denp) {
  __shared__ long long smq[5120];  // 40960 B, 8B-aligned
  unsigned char* sm = (unsigned char*)smq;
  const int tid = threadIdx.x;
  const int w = tid >> 6, l = tid & 63;
  const int l15 = l & 15, lh = l >> 4;
  const int b = blockIdx.y, sp = blockIdx.z;
  const int n0 = blockIdx.x * 128;
  const int kvbase = sp * 1024;

  // Q fragments (fp8): row n0+w*32+qs*16+l15, 8 bytes at k = ko*32 + lh*8
  long long qf0[4], qf1[4];
  {
    const unsigned char* q0 = Qb8 + (size_t)(b * 4096 + n0 + w * 32 + l15) * 128 + lh * 8;
    const unsigned char* q1 = q0 + 16 * 128;
#pragma unroll
    for (int ko = 0; ko < 4; ++ko) {
      qf0[ko] = *(const long long*)(q0 + ko * 32);
      qf1[ko] = *(const long long*)(q1 + ko * 32);
    }
  }
  // LDS bytes: K0 [0,8192) K1 [8192,16384) V0 [16384,24576) V1 [24576,32768)
  //            sP [32768,40960) (4 waves x 2048: [32 q][64 m])
  unsigned char* sPw = sm + 32768 + w * 2048;

  f32x4 yacc0[8], yacc1[8];
#pragma unroll
  for (int i = 0; i < 8; ++i) {
    yacc0[i] = (f32x4){0.f, 0.f, 0.f, 0.f};
    yacc1[i] = (f32x4){0.f, 0.f, 0.f, 0.f};
  }
  float den0 = 0.f, den1 = 0.f;

  const unsigned char* Kbase = Kb8 + (size_t)(b * 4096 + kvbase) * 128;
  const unsigned char* Vbase = Vtb8 + (size_t)(b * 128) * 4096 + kvbase;

// stage tile T into buffer BUFO (0 or 8192): K rows 128B (8x16B blocks, src block
// t ^ (row&7)); V rows 64B (4x16B blocks, src block t ^ (d&3)).
#define STAGE(T, BUFO)                                                               \
  {                                                                                  \
    const int koff_ = (T) * 64;                                                      \
    _Pragma("unroll")                                                                \
    for (int it = 0; it < 2; ++it) {                                                 \
      int krow = w * 16 + it * 8 + (l >> 3);                                         \
      gl16(Kbase + (size_t)(koff_ + krow) * 128 + (((l & 7) ^ (krow & 7)) << 4),     \
           sm + (BUFO) + (w * 16 + it * 8) * 128);                                   \
      int vrow = w * 32 + it * 16 + (l >> 2);                                        \
      gl16(Vbase + (size_t)vrow * 4096 + koff_ + (((l & 3) ^ (vrow & 3)) << 4),      \
           sm + 16384 + (BUFO) + (w * 32 + it * 16) * 64);                           \
    }                                                                                \
  }

  STAGE(0, 0)
  for (int t = 0; t < 16; ++t) {
    const int co = (t & 1) * 8192;
    unsigned char* kb = sm + co;
    unsigned char* vb = sm + 16384 + co;
    __syncthreads();  // drains vmcnt(0): buf[cur] ready; buf[cur^1] readers done
    if (t + 1 < 16) {
      STAGE(t + 1, co ^ 8192)
    }
    // QK^T (fp8): 4 ko x 4 mt, each ak (8B) feeds both q-sets
    f32x4 sacc0[4], sacc1[4];
#pragma unroll
    for (int mt = 0; mt < 4; ++mt) {
      sacc0[mt] = (f32x4){0.f, 0.f, 0.f, 0.f};
      sacc1[mt] = (f32x4){0.f, 0.f, 0.f, 0.f};
    }
    __builtin_amdgcn_s_setprio(1);
#pragma unroll
    for (int ko = 0; ko < 4; ++ko) {
#pragma unroll
      for (int mt = 0; mt < 4; ++mt) {
        int m = mt * 16 + l15;
        long long ak = *(const long long*)(
            kb + m * 128 + (((ko * 4 + lh) ^ ((m & 7) << 1)) << 3));
        sacc0[mt] = __builtin_amdgcn_mfma_f32_16x16x32_fp8_fp8(ak, qf0[ko], sacc0[mt], 0, 0, 0);
        sacc1[mt] = __builtin_amdgcn_mfma_f32_16x16x32_fp8_fp8(ak, qf1[ko], sacc1[mt], 0, 0, 0);
      }
    }
    __builtin_amdgcn_s_setprio(0);
    // softmax: p = exp2(sacc/16) (Q prescaled x16); pack fp8 via HW cvt builtin.
    // sP[row=qs*16+l15][m]: chunk c=mt*2+(lh>>1), slot = c ^ (l15&7), byte (lh&1)*4.
#define SOFTMAX_SET(SACC, ROWB, DEN)                                                 \
    {                                                                                \
      float rs = 0.f;                                                                \
      _Pragma("unroll")                                                              \
      for (int mt = 0; mt < 4; ++mt) {                                               \
        float e0 = __builtin_amdgcn_exp2f(SACC[mt][0] * 0.0625f);                    \
        float e1 = __builtin_amdgcn_exp2f(SACC[mt][1] * 0.0625f);                    \
        float e2 = __builtin_amdgcn_exp2f(SACC[mt][2] * 0.0625f);                    \
        float e3 = __builtin_amdgcn_exp2f(SACC[mt][3] * 0.0625f);                    \
        rs += (e0 + e1) + (e2 + e3);                                                 \
        int pk = __builtin_amdgcn_cvt_pk_fp8_f32(e0, e1, 0, false);                  \
        pk = __builtin_amdgcn_cvt_pk_fp8_f32(e2, e3, pk, true);                      \
        *(int*)(sPw + ((ROWB) + l15) * 64 +                                          \
                (((mt * 2 + (lh >> 1)) ^ (l15 & 7)) << 3) + (lh & 1) * 4) = pk;      \
      }                                                                              \
      rs += __shfl_xor(rs, 16);                                                      \
      rs += __shfl_xor(rs, 32);                                                      \
      DEN += rs;                                                                     \
    }
    SOFTMAX_SET(sacc0, 0, den0)
    SOFTMAX_SET(sacc1, 16, den1)
    // PV (fp8): 2 ko x 8 dt; av (8B) feeds both q-sets; bp from wave-private sP.
    __builtin_amdgcn_s_setprio(1);
#pragma unroll
    for (int ko = 0; ko < 2; ++ko) {
      long long bp0 = *(const long long*)(
          sPw + l15 * 64 + (((ko * 4 + lh) ^ (l15 & 7)) << 3));
      long long bp1 = *(const long long*)(
          sPw + (16 + l15) * 64 + (((ko * 4 + lh) ^ (l15 & 7)) << 3));
#pragma unroll
      for (int dt = 0; dt < 8; ++dt) {
        int d = dt * 16 + l15;
        long long av = *(const long long*)(
            vb + d * 64 + (((ko * 4 + lh) ^ ((d & 3) << 1)) << 3));
        yacc0[dt] = __builtin_amdgcn_mfma_f32_16x16x32_fp8_fp8(av, bp0, yacc0[dt], 0, 0, 0);
        yacc1[dt] = __builtin_amdgcn_mfma_f32_16x16x32_fp8_fp8(av, bp1, yacc1[dt], 0, 0, 0);
      }
    }
    __builtin_amdgcn_s_setprio(0);
  }
  // epilogue: unnormalized bf16 partial Y[n][p] and f32 den (both q-sets)
  {
    unsigned short* Yt = Ytp + (size_t)(sp * 4 + b) * 524288 +
                         (size_t)(n0 + w * 32 + l15) * 128;
#pragma unroll
    for (int dt = 0; dt < 8; ++dt) {
      ushort4 us;
      us.x = f2bf(yacc0[dt][0]); us.y = f2bf(yacc0[dt][1]);
      us.z = f2bf(yacc0[dt][2]); us.w = f2bf(yacc0[dt][3]);
      *(ushort4*)(Yt + dt * 16 + lh * 4) = us;
    }
    unsigned short* Yt1 = Yt + 16 * 128;
#pragma unroll
    for (int dt = 0; dt < 8; ++dt) {
      ushort4 us;
      us.x = f2bf(yacc1[dt][0]); us.y = f2bf(yacc1[dt][1]);
      us.z = f2bf(yacc1[dt][2]); us.w = f2bf(yacc1[dt][3]);
      *(ushort4*)(Yt1 + dt * 16 + lh * 4) = us;
    }
    if (lh == 0) {
      denp[(size_t)(sp * 4 + b) * 4096 + n0 + w * 32 + l15] = den0;
      denp[(size_t)(sp * 4 + b) * 4096 + n0 + w * 32 + 16 + l15] = den1;
    }
  }
}

// ---------------- 3) zbn: z = Wz*y + bz via MFMA; bf16 Z store; BN partials ----------------
__global__ __launch_bounds__(256, 4) void zbn_kernel(
    const unsigned short* __restrict__ Ytp, const float* __restrict__ denp,
    const float* __restrict__ Wz, const float* __restrict__ bz,
    unsigned short* __restrict__ Zb, float* __restrict__ S1p, float* __restrict__ S2p) {
  __shared__ unsigned short sY[64 * 128];
  __shared__ unsigned short sW[64 * 128];
  __shared__ float sDen[64];
  const int tid = threadIdx.x;
  const int w = tid >> 6, l = tid & 63;
  const int l15 = l & 15, lh = l >> 4;
  const int bx = blockIdx.x;
  const int b = blockIdx.y;
  const int n0 = bx * 64;
  const int c0 = blockIdx.z * 64;
  if (tid < 64) {
    float s = 0.f;
#pragma unroll
    for (int sp = 0; sp < 4; ++sp) s += denp[sp * 16384 + b * 4096 + n0 + tid];
    sDen[tid] = 1.0f / s;
  }
  __syncthreads();
#pragma unroll
  for (int it = 0; it < 4; ++it) {
    int e = it * 256 + tid;
    int n = e >> 4, pc = e & 15;
    size_t o = (size_t)b * 524288 + (size_t)(n0 + n) * 128 + pc * 8;
    float a0 = 0, a1 = 0, a2 = 0, a3 = 0, a4 = 0, a5 = 0, a6 = 0, a7 = 0;
#pragma unroll
    for (int sp = 0; sp < 4; ++sp) {
      uint4 v = *(const uint4*)(Ytp + (size_t)sp * 2097152 + o);
      a0 += bflo(v.x); a1 += bfhi(v.x);
      a2 += bflo(v.y); a3 += bfhi(v.y);
      a4 += bflo(v.z); a5 += bfhi(v.z);
      a6 += bflo(v.w); a7 += bfhi(v.w);
    }
    float idn = sDen[n];
    ushort8v us;
    us[0] = f2bf(a0 * idn); us[1] = f2bf(a1 * idn);
    us[2] = f2bf(a2 * idn); us[3] = f2bf(a3 * idn);
    us[4] = f2bf(a4 * idn); us[5] = f2bf(a5 * idn);
    us[6] = f2bf(a6 * idn); us[7] = f2bf(a7 * idn);
    *(ushort8v*)(sY + n * 128 + ((pc ^ (n & 7)) << 3)) = us;
  }
#pragma unroll
  for (int it = 0; it < 4; ++it) {
    int e = it * 256 + tid;
    int c = e >> 4, pc = e & 15;
    const float* wsrc = Wz + (size_t)(c0 + c) * 128 + pc * 8;
    float4 wa = *(const float4*)(wsrc);
    float4 wb = *(const float4*)(wsrc + 4);
    ushort8v us;
    us[0] = f2bf(wa.x); us[1] = f2bf(wa.y); us[2] = f2bf(wa.z); us[3] = f2bf(wa.w);
    us[4] = f2bf(wb.x); us[5] = f2bf(wb.y); us[6] = f2bf(wb.z); us[7] = f2bf(wb.w);
    *(ushort8v*)(sW + c * 128 + ((pc ^ (c & 7)) << 3)) = us;
  }
  __syncthreads();
  f32x4 acc[4];
#pragma unroll
  for (int nt = 0; nt < 4; ++nt) acc[nt] = (f32x4){0.f, 0.f, 0.f, 0.f};
  const int crow = w * 16 + l15;
#pragma unroll
  for (int ko = 0; ko < 4; ++ko) {
    bf16x8 aw = *(const bf16x8*)(sW + crow * 128 + (((lh + 4 * ko) ^ (crow & 7)) << 3));
#pragma unroll
    for (int nt = 0; nt < 4; ++nt) {
      int nrow = nt * 16 + l15;
      bf16x8 by = *(const bf16x8*)(sY + nrow * 128 + (((lh + 4 * ko) ^ (nrow & 7)) << 3));
      acc[nt] = __builtin_amdgcn_mfma_f32_16x16x32_bf16(aw, by, acc[nt], 0, 0, 0);
    }
  }
  const int cb = c0 + w * 16 + lh * 4;
  float4 bzv = *(const float4*)(bz + cb);
  const float* bzf = (const float*)&bzv;
#pragma unroll
  for (int r = 0; r < 4; ++r) {
    float s1 = 0.f, s2 = 0.f;
#pragma unroll
    for (int nt = 0; nt < 4; ++nt) {
      float z = acc[nt][r] + bzf[r];
      Zb[(size_t)(b * 256 + cb + r) * 4096 + n0 + nt * 16 + l15] = f2bf(z);
      s1 += z;
      s2 += z * z;
    }
#pragma unroll
    for (int m = 1; m < 16; m <<= 1) {
      s1 += __shfl_xor(s1, m);
      s2 += __shfl_xor(s2, m);
    }
    if (l15 == 0) {
      S1p[(size_t)(cb + r) * 256 + b * 64 + bx] = s1;
      S2p[(size_t)(cb + r) * 256 + b * 64 + bx] = s2;
    }
  }
}

// ---------------- 4) BN finalize: reduce 256 partials per channel ----------------
__global__ __launch_bounds__(256) void bnfin_kernel(
    const float* __restrict__ S1p, const float* __restrict__ S2p,
    const float* __restrict__ gamma, const float* __restrict__ beta,
    float* __restrict__ Scale, float* __restrict__ Shift) {
  __shared__ float r1[4], r2[4];
  const int c = blockIdx.x, tid = threadIdx.x;
  float s1 = S1p[(size_t)c * 256 + tid];
  float s2 = S2p[(size_t)c * 256 + tid];
#pragma unroll
  for (int m = 1; m < 64; m <<= 1) {
    s1 += __shfl_xor(s1, m);
    s2 += __shfl_xor(s2, m);
  }
  if ((tid & 63) == 0) { r1[tid >> 6] = s1; r2[tid >> 6] = s2; }
  __syncthreads();
  if (tid == 0) {
    float S1t = (r1[0] + r1[1]) + (r1[2] + r1[3]);
    float S2t = (r2[0] + r2[1]) + (r2[2] + r2[3]);
    const float inv_cnt = 1.0f / 16384.0f;  // B*N
    float mean = S1t * inv_cnt;
    float var = fmaxf(S2t * inv_cnt - mean * mean, 0.0f);
    float inv = rsqrtf(var + 1e-5f);
    float sc = gamma[c] * inv;
    Scale[c] = sc;
    Shift[c] = beta[c] - mean * sc;
  }
}

// ---------------- 5) out = z*scale + shift + x (bf16 Z, 8 elems/thread) ----------------
__global__ __launch_bounds__(256) void out_kernel(
    const unsigned short* __restrict__ Zb, const float* __restrict__ x,
    const float* __restrict__ Scale, const float* __restrict__ Shift,
    float* __restrict__ out) {
  int i8 = blockIdx.x * 256 + threadIdx.x;  // 0..524287
  size_t flat = (size_t)i8 * 8;
  int c = ((int)(flat >> 12)) & 255;
  uint4 zv = *(const uint4*)(Zb + flat);
  float4 xa = *(const float4*)(x + flat);
  float4 xb = *(const float4*)(x + flat + 4);
  float sc = Scale[c], sh = Shift[c];
  float4 oa, ob;
  oa.x = bflo(zv.x) * sc + sh + xa.x;
  oa.y = bfhi(zv.x) * sc + sh + xa.y;
  oa.z = bflo(zv.y) * sc + sh + xa.z;
  oa.w = bfhi(zv.y) * sc + sh + xa.w;
  ob.x = bflo(zv.z) * sc + sh + xb.x;
  ob.y = bfhi(zv.z) * sc + sh + xb.y;
  ob.z = bflo(zv.w) * sc + sh + xb.z;
  ob.w = bfhi(zv.w) * sc + sh + xb.w;
  *(float4*)(out + flat) = oa;
  *(float4*)(out + flat + 4) = ob;
}

extern "C" void kernel_launch(void* const* d_in, const int* in_sizes, int n_in,
                              void* d_out, int out_size, void* d_ws, size_t ws_size,
                              hipStream_t stream) {
  (void)in_sizes; (void)n_in; (void)out_size; (void)ws_size;
  const float* x = (const float*)d_in[0];
  const float* Wt = (const float*)d_in[1];
  const float* bt = (const float*)d_in[2];
  const float* Wp = (const float*)d_in[3];
  const float* bp = (const float*)d_in[4];
  const float* Wg = (const float*)d_in[5];
  const float* bg = (const float*)d_in[6];
  const float* Wz = (const float*)d_in[7];
  const float* bz = (const float*)d_in[8];
  const float* gamma = (const float*)d_in[9];
  const float* beta = (const float*)d_in[10];

  unsigned char* Qb8 = (unsigned char*)d_ws;         // 2 MB (fp8)
  unsigned char* Kb8 = Qb8 + 2097152;                // 2 MB
  unsigned char* Vtb8 = Kb8 + 2097152;               // 2 MB
  unsigned short* Ytp = (unsigned short*)(Vtb8 + 2097152);  // 16 MB bf16 partials
  float* denp = (float*)(Ytp + 8388608);             // 256 KB
  float* Zr = denp + 65536;                          // 16 MB region (Zb uses 8 MB)
  float* Scale = Zr + 4194304;                       // 1 KB
  float* Shift = Scale + 256;

  // liveness aliases:
  unsigned short* Zb = (unsigned short*)Zr;          // bf16 Z
  unsigned short* xT = (unsigned short*)Zr;          // dead before zbn writes Zb
  unsigned short* Wb = (unsigned short*)denp;        // 192KB, dead before attn writes denp
  float* S1p = (float*)Qb8;                          // used after attn (Qb8 dead)
  float* S2p = S1p + 65536;

  prep_kernel<<<dim3(80, 4), 256, 0, stream>>>(x, Wt, Wp, Wg, xT, Wb);
  proj_kernel<<<dim3(64, 4, 3), 256, 0, stream>>>(xT, Wb, bt, bp, bg, Qb8, Kb8, Vtb8);
  attn_kernel<<<dim3(32, 4, 4), 256, 0, stream>>>(Qb8, Kb8, Vtb8, Ytp, denp);
  zbn_kernel<<<dim3(64, 4, 4), 256, 0, stream>>>(Ytp, denp, Wz, bz, Zb, S1p, S2p);
  bnfin_kernel<<<256, 256, 0, stream>>>(S1p, S2p, gamma, beta, Scale, Shift);
  out_kernel<<<2048, 256, 0, stream>>>(Zb, x, Scale, Shift, (float*)d_out);
}

// Round 18
// 82.387 us; speedup vs baseline: 1.0453x; 1.0453x over previous
//
#include <hip/hip_runtime.h>

// NonLocal block: B=4, C=256, P=128, H=W=64, N=4096.
// prep -> proj2 (MFMA bf16 -> fp8 Q/K/V) -> attn v10 (fp8 MFMA flash, 16B LDS
// reads via k-order relabel sigma; dbuf; 40KB LDS) -> zbn -> bnfin -> out.
// R18: R17's 8B fp8 reads underused banks (K rows 128B bank-aligned: 16/32 banks;
// V/sP 64B rows: 4-way) -> conflicts 3x, gain eaten. MFMA is k-order-invariant if
// BOTH operands use the same k->slot map: relabel so each lane's call fragments
// are contiguous 16/32B -> all reads b128, full bank spread. Staging unchanged.

#define SCALE_ 0.08838834764831845f    // 1/sqrt(128)
#define QSCALE_ 2.0404384761599213f    // 1/sqrt(128) * log2(e) * 16

typedef __bf16 bf16x8 __attribute__((ext_vector_type(8)));
typedef float f32x4 __attribute__((ext_vector_type(4)));
typedef unsigned short ushort8v __attribute__((ext_vector_type(8)));
typedef long long llx2 __attribute__((ext_vector_type(2)));

__device__ inline unsigned short f2bf(float f) {  // RNE float->bf16
  unsigned int u = __float_as_uint(f);
  u += 0x7fffu + ((u >> 16) & 1u);
  return (unsigned short)(u >> 16);
}
__device__ inline float bflo(unsigned int u) { return __uint_as_float(u << 16); }
__device__ inline float bfhi(unsigned int u) { return __uint_as_float(u & 0xffff0000u); }

// RNE float -> OCP e4m3fn (bias 7, max 448, min normal 2^-6, denorm quantum 2^-9)
__device__ inline unsigned char f2fp8(float f) {
  unsigned u = __float_as_uint(f);
  unsigned sign = (u >> 24) & 0x80u;
  unsigned a = u & 0x7fffffffu;
  if (a >= 0x43E00000u) return (unsigned char)(sign | 0x7Eu);  // clamp 448
  if (a >= 0x3C800000u) {  // >= 2^-6: normal
    unsigned r = a + 0x0007FFFFu + ((a >> 20) & 1u);  // RNE to 3 mantissa bits
    r &= 0xFFF00000u;
    int e8 = (int)((r >> 23) & 0xFFu) - 120;  // -127+7
    unsigned m3 = (r >> 20) & 7u;
    return (unsigned char)(sign | ((unsigned)e8 << 3) | m3);
  }
  float q = __uint_as_float(a) * 512.0f;  // units of 2^-9
  int d = (int)rintf(q);
  if (d >= 8) return (unsigned char)(sign | 0x08u);
  return (unsigned char)(sign | (unsigned)d);
}

// async global->LDS, 16B per lane; LDS dest = wave-uniform base + lane*16 (linear).
__device__ inline void gl16(const void* g, void* l) {
  __builtin_amdgcn_global_load_lds(
      (const __attribute__((address_space(1))) unsigned int*)(g),
      (__attribute__((address_space(3))) unsigned int*)(l), 16, 0, 0);
}

// ---------------- 0) prep: xT[b][n][c] bf16 + Wb[3][128][256] bf16 ----------------
__global__ __launch_bounds__(256) void prep_kernel(
    const float* __restrict__ x,
    const float* __restrict__ Wt, const float* __restrict__ Wp, const float* __restrict__ Wg,
    unsigned short* __restrict__ xT, unsigned short* __restrict__ Wb) {
  const int tid = threadIdx.x;
  const int bx = blockIdx.x, b = blockIdx.y;
  if (bx >= 64) {
    if (b != 0) return;
#pragma unroll
    for (int it = 0; it < 3; ++it) {
      int k = (bx - 64) * 256 + tid + it * 4096;  // 0..12287
      const float* src = (k < 4096 ? Wt : (k < 8192 ? Wp : Wg)) + (size_t)(k & 4095) * 8;
      float4 a = *(const float4*)src, c = *(const float4*)(src + 4);
      ushort8v us;
      us[0] = f2bf(a.x); us[1] = f2bf(a.y); us[2] = f2bf(a.z); us[3] = f2bf(a.w);
      us[4] = f2bf(c.x); us[5] = f2bf(c.y); us[6] = f2bf(c.z); us[7] = f2bf(c.w);
      *(ushort8v*)(Wb + (size_t)k * 8) = us;
    }
    return;
  }
  __shared__ float sT[128 * 68];
  const int w = tid >> 6, l = tid & 63;
  const int n0 = bx * 64;
  for (int half = 0; half < 2; ++half) {
    if (half) __syncthreads();
#pragma unroll
    for (int it = 0; it < 8; ++it) {
      int e = it * 256 + tid;
      int c = e >> 4, n4 = e & 15;
      float4 v = *(const float4*)(x + (size_t)(b * 256 + half * 128 + c) * 4096 + n0 + n4 * 4);
      *(float4*)(sT + c * 68 + n4 * 4) = v;
    }
    __syncthreads();
#pragma unroll
    for (int it = 0; it < 4; ++it) {
      int c8 = it * 4 + w;
      int n = l;
      ushort8v us;
#pragma unroll
      for (int j = 0; j < 8; ++j) us[j] = f2bf(sT[(c8 * 8 + j) * 68 + n]);
      *(ushort8v*)(xT + (size_t)b * 1048576 + (size_t)(n0 + n) * 256 + half * 128 + c8 * 8) = us;
    }
  }
}

// ---------------- 1) proj2: Q,K,Vt via bf16 MFMA; outputs fp8 ----------------
__global__ __launch_bounds__(256, 3) void proj_kernel(
    const unsigned short* __restrict__ xT, const unsigned short* __restrict__ Wb,
    const float* __restrict__ bt, const float* __restrict__ bp, const float* __restrict__ bg,
    unsigned char* __restrict__ Qb8, unsigned char* __restrict__ Kb8,
    unsigned char* __restrict__ Vtb8) {
  __shared__ unsigned short sX[64 * 256];
  __shared__ unsigned short sW[128 * 64];
  const int tid = threadIdx.x;
  const int w = tid >> 6, l = tid & 63;
  const int l15 = l & 15, lh = l >> 4;
  const int n0 = blockIdx.x * 64;
  const int b = blockIdx.y;
  const int sel = blockIdx.z;
  const unsigned short* xTb = xT + (size_t)b * 1048576;
  const unsigned short* Ws = Wb + (size_t)sel * 32768;
#pragma unroll
  for (int it = 0; it < 8; ++it) {
    int row = w * 16 + it * 2 + (l >> 5);
    int s = l & 31;
    int src = (s & 24) | ((s & 7) ^ (row & 7));
    gl16(xTb + (size_t)(n0 + row) * 256 + src * 8, sX + (w * 16 + it * 2) * 256);
  }
  f32x4 acc[2][4];
#pragma unroll
  for (int mt = 0; mt < 2; ++mt)
#pragma unroll
    for (int nt = 0; nt < 4; ++nt) acc[mt][nt] = (f32x4){0.f, 0.f, 0.f, 0.f};

  for (int ko4 = 0; ko4 < 4; ++ko4) {
    __syncthreads();
#pragma unroll
    for (int it = 0; it < 4; ++it) {
      int p = w * 32 + it * 8 + (l >> 3);
      int s = l & 7;
      gl16(Ws + (size_t)p * 256 + ko4 * 64 + ((s ^ (p & 7)) * 8),
           sW + (w * 32 + it * 8) * 64);
    }
    __syncthreads();
#pragma unroll
    for (int ko2 = 0; ko2 < 2; ++ko2) {
      bf16x8 af[2];
#pragma unroll
      for (int mt = 0; mt < 2; ++mt) {
        int p = w * 32 + mt * 16 + l15;
        af[mt] = *(const bf16x8*)(sW + p * 64 + (((ko2 * 4 + lh) ^ (p & 7)) << 3));
      }
#pragma unroll
      for (int nt = 0; nt < 4; ++nt) {
        int n = nt * 16 + l15;
        int ci = ko4 * 8 + ko2 * 4 + lh;
        int slot = (ci & 24) | ((ci & 7) ^ (n & 7));
        bf16x8 bfv = *(const bf16x8*)(sX + n * 256 + (slot << 3));
#pragma unroll
        for (int mt = 0; mt < 2; ++mt)
          acc[mt][nt] = __builtin_amdgcn_mfma_f32_16x16x32_bf16(af[mt], bfv, acc[mt][nt], 0, 0, 0);
      }
    }
  }
  const float* bias = sel == 0 ? bt : (sel == 1 ? bp : bg);
  const float scl = sel == 0 ? QSCALE_ : 1.0f;
#pragma unroll
  for (int mt = 0; mt < 2; ++mt) {
    int pb = w * 32 + mt * 16 + lh * 4;
    float4 bv = *(const float4*)(bias + pb);
    const float* bvf = (const float*)&bv;
    if (sel < 2) {
      unsigned char* dst = (sel == 0 ? Qb8 : Kb8) + (size_t)b * 524288;
#pragma unroll
      for (int nt = 0; nt < 4; ++nt) {
        uchar4 us;
        us.x = f2fp8((acc[mt][nt][0] + bv.x) * scl);
        us.y = f2fp8((acc[mt][nt][1] + bv.y) * scl);
        us.z = f2fp8((acc[mt][nt][2] + bv.z) * scl);
        us.w = f2fp8((acc[mt][nt][3] + bv.w) * scl);
        *(uchar4*)(dst + (size_t)(n0 + nt * 16 + l15) * 128 + pb) = us;
      }
    } else {
      unsigned char* dst = Vtb8 + (size_t)b * 524288;
#pragma unroll
      for (int nt = 0; nt < 4; ++nt)
#pragma unroll
        for (int r = 0; r < 4; ++r)
          dst[(size_t)(pb + r) * 4096 + n0 + nt * 16 + l15] = f2fp8(acc[mt][nt][r] + bvf[r]);
    }
  }
}

// ---------------- 2) attn v10: fp8, 16B LDS reads via sigma relabel ----------------
// grid (32 qb, 4 b, 4 split); 256 thr = 4 waves; wave w owns q rows n0+w*32..+31
// as two 16-row sets. LDS 40KB: K dbuf 2x8K [64m][128d], V dbuf 2x8K [128d][64m],
// sP 4x2K [32q][64m]. Sigma: K call ko <-> d-chunk (lh*4+ko)*8 (lane 32B contig);
// V/P call ko <-> m-chunk (lh*2+ko)*8 (lane 16B contig). Both operands of every
// MFMA use the same sigma -> exact. All hot reads = b128, full bank spread.
__global__ __launch_bounds__(256, 3) void attn_kernel(
    const unsigned char* __restrict__ Qb8, const unsigned char* __restrict__ Kb8,
    const unsigned char* __restrict__ Vtb8, unsigned short* __restrict__ Ytp,
    float* __restrict__ denp) {
  __shared__ f32x4 smq[2560];  // 40960 B, 16B aligned
  unsigned char* sm = (unsigned char*)smq;
  const int tid = threadIdx.x;
  const int w = tid >> 6, l = tid & 63;
  const int l15 = l & 15, lh = l >> 4;
  const int b = blockIdx.y, sp = blockIdx.z;
  const int n0 = blockIdx.x * 128;
  const int kvbase = sp * 1024;

  // Q fragments (sigma): qf[ko] = Q bytes d in [lh*32 + ko*8, +8), contiguous 32B.
  long long qf0[4], qf1[4];
  {
    const unsigned char* q0 = Qb8 + (size_t)(b * 4096 + n0 + w * 32 + l15) * 128 + lh * 32;
    const unsigned char* q1 = q0 + 16 * 128;
#pragma unroll
    for (int ko = 0; ko < 4; ++ko) {
      qf0[ko] = *(const long long*)(q0 + ko * 8);
      qf1[ko] = *(const long long*)(q1 + ko * 8);
    }
  }
  // LDS bytes: K0 [0,8192) K1 [8192,16384) V0 [16384,24576) V1 [24576,32768)
  //            sP [32768,40960) (4 waves x 2048: [32 q][64 m])
  unsigned char* sPw = sm + 32768 + w * 2048;

  f32x4 yacc0[8], yacc1[8];
#pragma unroll
  for (int i = 0; i < 8; ++i) {
    yacc0[i] = (f32x4){0.f, 0.f, 0.f, 0.f};
    yacc1[i] = (f32x4){0.f, 0.f, 0.f, 0.f};
  }
  float den0 = 0.f, den1 = 0.f;

  const unsigned char* Kbase = Kb8 + (size_t)(b * 4096 + kvbase) * 128;
  const unsigned char* Vbase = Vtb8 + (size_t)(b * 128) * 4096 + kvbase;

// stage tile T into buffer BUFO (0 or 8192): 16B-block source permutation
// (physical block pb holds global block pb ^ (row-key)) -- unchanged from R17.
#define STAGE(T, BUFO)                                                               \
  {                                                                                  \
    const int koff_ = (T) * 64;                                                      \
    _Pragma("unroll")                                                                \
    for (int it = 0; it < 2; ++it) {                                                 \
      int krow = w * 16 + it * 8 + (l >> 3);                                         \
      gl16(Kbase + (size_t)(koff_ + krow) * 128 + (((l & 7) ^ (krow & 7)) << 4),     \
           sm + (BUFO) + (w * 16 + it * 8) * 128);                                   \
      int vrow = w * 32 + it * 16 + (l >> 2);                                        \
      gl16(Vbase + (size_t)vrow * 4096 + koff_ + (((l & 3) ^ (vrow & 3)) << 4),      \
           sm + 16384 + (BUFO) + (w * 32 + it * 16) * 64);                           \
    }                                                                                \
  }

  STAGE(0, 0)
  for (int t = 0; t < 16; ++t) {
    const int co = (t & 1) * 8192;
    unsigned char* kb = sm + co;
    unsigned char* vb = sm + 16384 + co;
    __syncthreads();  // drains vmcnt(0): buf[cur] ready; buf[cur^1] readers done
    if (t + 1 < 16) {
      STAGE(t + 1, co ^ 8192)
    }
    // QK^T: per mt, 2 b128 reads give all 4 ko fragments (d [lh*32, +32)).
    f32x4 sacc0[4], sacc1[4];
#pragma unroll
    for (int mt = 0; mt < 4; ++mt) {
      sacc0[mt] = (f32x4){0.f, 0.f, 0.f, 0.f};
      sacc1[mt] = (f32x4){0.f, 0.f, 0.f, 0.f};
    }
    __builtin_amdgcn_s_setprio(1);
#pragma unroll
    for (int mt = 0; mt < 4; ++mt) {
      int m = mt * 16 + l15;
      llx2 k01 = *(const llx2*)(kb + m * 128 + (((lh * 2 + 0) ^ (m & 7)) << 4));
      llx2 k23 = *(const llx2*)(kb + m * 128 + (((lh * 2 + 1) ^ (m & 7)) << 4));
      sacc0[mt] = __builtin_amdgcn_mfma_f32_16x16x32_fp8_fp8(k01[0], qf0[0], sacc0[mt], 0, 0, 0);
      sacc1[mt] = __builtin_amdgcn_mfma_f32_16x16x32_fp8_fp8(k01[0], qf1[0], sacc1[mt], 0, 0, 0);
      sacc0[mt] = __builtin_amdgcn_mfma_f32_16x16x32_fp8_fp8(k01[1], qf0[1], sacc0[mt], 0, 0, 0);
      sacc1[mt] = __builtin_amdgcn_mfma_f32_16x16x32_fp8_fp8(k01[1], qf1[1], sacc1[mt], 0, 0, 0);
      sacc0[mt] = __builtin_amdgcn_mfma_f32_16x16x32_fp8_fp8(k23[0], qf0[2], sacc0[mt], 0, 0, 0);
      sacc1[mt] = __builtin_amdgcn_mfma_f32_16x16x32_fp8_fp8(k23[0], qf1[2], sacc1[mt], 0, 0, 0);
      sacc0[mt] = __builtin_amdgcn_mfma_f32_16x16x32_fp8_fp8(k23[1], qf0[3], sacc0[mt], 0, 0, 0);
      sacc1[mt] = __builtin_amdgcn_mfma_f32_16x16x32_fp8_fp8(k23[1], qf1[3], sacc1[mt], 0, 0, 0);
    }
    __builtin_amdgcn_s_setprio(0);
    // softmax: p = exp2(sacc/16); pack fp8; sP stored in PLAIN m-order with
    // 16B-block XOR: byte m=16mt+4lh -> block mt ^ (q&3), offset lh*4.
#define SOFTMAX_SET(SACC, ROWB, DEN)                                                 \
    {                                                                                \
      float rs = 0.f;                                                                \
      _Pragma("unroll")                                                              \
      for (int mt = 0; mt < 4; ++mt) {                                               \
        float e0 = __builtin_amdgcn_exp2f(SACC[mt][0] * 0.0625f);                    \
        float e1 = __builtin_amdgcn_exp2f(SACC[mt][1] * 0.0625f);                    \
        float e2 = __builtin_amdgcn_exp2f(SACC[mt][2] * 0.0625f);                    \
        float e3 = __builtin_amdgcn_exp2f(SACC[mt][3] * 0.0625f);                    \
        rs += (e0 + e1) + (e2 + e3);                                                 \
        int pk = __builtin_amdgcn_cvt_pk_fp8_f32(e0, e1, 0, false);                  \
        pk = __builtin_amdgcn_cvt_pk_fp8_f32(e2, e3, pk, true);                      \
        *(int*)(sPw + ((ROWB) + l15) * 64 + ((mt ^ (l15 & 3)) << 4) + lh * 4) = pk;  \
      }                                                                              \
      rs += __shfl_xor(rs, 16);                                                      \
      rs += __shfl_xor(rs, 32);                                                      \
      DEN += rs;                                                                     \
    }
    SOFTMAX_SET(sacc0, 0, den0)
    SOFTMAX_SET(sacc1, 16, den1)
    // PV: one b128 V read per dt serves both ko and both q-sets; sP read b128.
    // sigma: call ko slot (lh,j) <-> m = lh*16 + ko*8 + j (low/high 8B halves).
    __builtin_amdgcn_s_setprio(1);
    {
      llx2 bp0 = *(const llx2*)(sPw + l15 * 64 + ((lh ^ (l15 & 3)) << 4));
      llx2 bp1 = *(const llx2*)(sPw + (16 + l15) * 64 + ((lh ^ (l15 & 3)) << 4));
#pragma unroll
      for (int dt = 0; dt < 8; ++dt) {
        int d = dt * 16 + l15;
        llx2 av = *(const llx2*)(vb + d * 64 + ((lh ^ (d & 3)) << 4));
        yacc0[dt] = __builtin_amdgcn_mfma_f32_16x16x32_fp8_fp8(av[0], bp0[0], yacc0[dt], 0, 0, 0);
        yacc1[dt] = __builtin_amdgcn_mfma_f32_16x16x32_fp8_fp8(av[0], bp1[0], yacc1[dt], 0, 0, 0);
        yacc0[dt] = __builtin_amdgcn_mfma_f32_16x16x32_fp8_fp8(av[1], bp0[1], yacc0[dt], 0, 0, 0);
        yacc1[dt] = __builtin_amdgcn_mfma_f32_16x16x32_fp8_fp8(av[1], bp1[1], yacc1[dt], 0, 0, 0);
      }
    }
    __builtin_amdgcn_s_setprio(0);
  }
  // epilogue: unnormalized bf16 partial Y[n][p] and f32 den (both q-sets)
  {
    unsigned short* Yt = Ytp + (size_t)(sp * 4 + b) * 524288 +
                         (size_t)(n0 + w * 32 + l15) * 128;
#pragma unroll
    for (int dt = 0; dt < 8; ++dt) {
      ushort4 us;
      us.x = f2bf(yacc0[dt][0]); us.y = f2bf(yacc0[dt][1]);
      us.z = f2bf(yacc0[dt][2]); us.w = f2bf(yacc0[dt][3]);
      *(ushort4*)(Yt + dt * 16 + lh * 4) = us;
    }
    unsigned short* Yt1 = Yt + 16 * 128;
#pragma unroll
    for (int dt = 0; dt < 8; ++dt) {
      ushort4 us;
      us.x = f2bf(yacc1[dt][0]); us.y = f2bf(yacc1[dt][1]);
      us.z = f2bf(yacc1[dt][2]); us.w = f2bf(yacc1[dt][3]);
      *(ushort4*)(Yt1 + dt * 16 + lh * 4) = us;
    }
    if (lh == 0) {
      denp[(size_t)(sp * 4 + b) * 4096 + n0 + w * 32 + l15] = den0;
      denp[(size_t)(sp * 4 + b) * 4096 + n0 + w * 32 + 16 + l15] = den1;
    }
  }
}

// ---------------- 3) zbn: z = Wz*y + bz via MFMA; bf16 Z store; BN partials ----------------
__global__ __launch_bounds__(256, 4) void zbn_kernel(
    const unsigned short* __restrict__ Ytp, const float* __restrict__ denp,
    const float* __restrict__ Wz, const float* __restrict__ bz,
    unsigned short* __restrict__ Zb, float* __restrict__ S1p, float* __restrict__ S2p) {
  __shared__ unsigned short sY[64 * 128];
  __shared__ unsigned short sW[64 * 128];
  __shared__ float sDen[64];
  const int tid = threadIdx.x;
  const int w = tid >> 6, l = tid & 63;
  const int l15 = l & 15, lh = l >> 4;
  const int bx = blockIdx.x;
  const int b = blockIdx.y;
  const int n0 = bx * 64;
  const int c0 = blockIdx.z * 64;
  if (tid < 64) {
    float s = 0.f;
#pragma unroll
    for (int sp = 0; sp < 4; ++sp) s += denp[sp * 16384 + b * 4096 + n0 + tid];
    sDen[tid] = 1.0f / s;
  }
  __syncthreads();
#pragma unroll
  for (int it = 0; it < 4; ++it) {
    int e = it * 256 + tid;
    int n = e >> 4, pc = e & 15;
    size_t o = (size_t)b * 524288 + (size_t)(n0 + n) * 128 + pc * 8;
    float a0 = 0, a1 = 0, a2 = 0, a3 = 0, a4 = 0, a5 = 0, a6 = 0, a7 = 0;
#pragma unroll
    for (int sp = 0; sp < 4; ++sp) {
      uint4 v = *(const uint4*)(Ytp + (size_t)sp * 2097152 + o);
      a0 += bflo(v.x); a1 += bfhi(v.x);
      a2 += bflo(v.y); a3 += bfhi(v.y);
      a4 += bflo(v.z); a5 += bfhi(v.z);
      a6 += bflo(v.w); a7 += bfhi(v.w);
    }
    float idn = sDen[n];
    ushort8v us;
    us[0] = f2bf(a0 * idn); us[1] = f2bf(a1 * idn);
    us[2] = f2bf(a2 * idn); us[3] = f2bf(a3 * idn);
    us[4] = f2bf(a4 * idn); us[5] = f2bf(a5 * idn);
    us[6] = f2bf(a6 * idn); us[7] = f2bf(a7 * idn);
    *(ushort8v*)(sY + n * 128 + ((pc ^ (n & 7)) << 3)) = us;
  }
#pragma unroll
  for (int it = 0; it < 4; ++it) {
    int e = it * 256 + tid;
    int c = e >> 4, pc = e & 15;
    const float* wsrc = Wz + (size_t)(c0 + c) * 128 + pc * 8;
    float4 wa = *(const float4*)(wsrc);
    float4 wb = *(const float4*)(wsrc + 4);
    ushort8v us;
    us[0] = f2bf(wa.x); us[1] = f2bf(wa.y); us[2] = f2bf(wa.z); us[3] = f2bf(wa.w);
    us[4] = f2bf(wb.x); us[5] = f2bf(wb.y); us[6] = f2bf(wb.z); us[7] = f2bf(wb.w);
    *(ushort8v*)(sW + c * 128 + ((pc ^ (c & 7)) << 3)) = us;
  }
  __syncthreads();
  f32x4 acc[4];
#pragma unroll
  for (int nt = 0; nt < 4; ++nt) acc[nt] = (f32x4){0.f, 0.f, 0.f, 0.f};
  const int crow = w * 16 + l15;
#pragma unroll
  for (int ko = 0; ko < 4; ++ko) {
    bf16x8 aw = *(const bf16x8*)(sW + crow * 128 + (((lh + 4 * ko) ^ (crow & 7)) << 3));
#pragma unroll
    for (int nt = 0; nt < 4; ++nt) {
      int nrow = nt * 16 + l15;
      bf16x8 by = *(const bf16x8*)(sY + nrow * 128 + (((lh + 4 * ko) ^ (nrow & 7)) << 3));
      acc[nt] = __builtin_amdgcn_mfma_f32_16x16x32_bf16(aw, by, acc[nt], 0, 0, 0);
    }
  }
  const int cb = c0 + w * 16 + lh * 4;
  float4 bzv = *(const float4*)(bz + cb);
  const float* bzf = (const float*)&bzv;
#pragma unroll
  for (int r = 0; r < 4; ++r) {
    float s1 = 0.f, s2 = 0.f;
#pragma unroll
    for (int nt = 0; nt < 4; ++nt) {
      float z = acc[nt][r] + bzf[r];
      Zb[(size_t)(b * 256 + cb + r) * 4096 + n0 + nt * 16 + l15] = f2bf(z);
      s1 += z;
      s2 += z * z;
    }
#pragma unroll
    for (int m = 1; m < 16; m <<= 1) {
      s1 += __shfl_xor(s1, m);
      s2 += __shfl_xor(s2, m);
    }
    if (l15 == 0) {
      S1p[(size_t)(cb + r) * 256 + b * 64 + bx] = s1;
      S2p[(size_t)(cb + r) * 256 + b * 64 + bx] = s2;
    }
  }
}

// ---------------- 4) BN finalize: reduce 256 partials per channel ----------------
__global__ __launch_bounds__(256) void bnfin_kernel(
    const float* __restrict__ S1p, const float* __restrict__ S2p,
    const float* __restrict__ gamma, const float* __restrict__ beta,
    float* __restrict__ Scale, float* __restrict__ Shift) {
  __shared__ float r1[4], r2[4];
  const int c = blockIdx.x, tid = threadIdx.x;
  float s1 = S1p[(size_t)c * 256 + tid];
  float s2 = S2p[(size_t)c * 256 + tid];
#pragma unroll
  for (int m = 1; m < 64; m <<= 1) {
    s1 += __shfl_xor(s1, m);
    s2 += __shfl_xor(s2, m);
  }
  if ((tid & 63) == 0) { r1[tid >> 6] = s1; r2[tid >> 6] = s2; }
  __syncthreads();
  if (tid == 0) {
    float S1t = (r1[0] + r1[1]) + (r1[2] + r1[3]);
    float S2t = (r2[0] + r2[1]) + (r2[2] + r2[3]);
    const float inv_cnt = 1.0f / 16384.0f;  // B*N
    float mean = S1t * inv_cnt;
    float var = fmaxf(S2t * inv_cnt - mean * mean, 0.0f);
    float inv = rsqrtf(var + 1e-5f);
    float sc = gamma[c] * inv;
    Scale[c] = sc;
    Shift[c] = beta[c] - mean * sc;
  }
}

// ---------------- 5) out = z*scale + shift + x (bf16 Z, 8 elems/thread) ----------------
__global__ __launch_bounds__(256) void out_kernel(
    const unsigned short* __restrict__ Zb, const float* __restrict__ x,
    const float* __restrict__ Scale, const float* __restrict__ Shift,
    float* __restrict__ out) {
  int i8 = blockIdx.x * 256 + threadIdx.x;  // 0..524287
  size_t flat = (size_t)i8 * 8;
  int c = ((int)(flat >> 12)) & 255;
  uint4 zv = *(const uint4*)(Zb + flat);
  float4 xa = *(const float4*)(x + flat);
  float4 xb = *(const float4*)(x + flat + 4);
  float sc = Scale[c], sh = Shift[c];
  float4 oa, ob;
  oa.x = bflo(zv.x) * sc + sh + xa.x;
  oa.y = bfhi(zv.x) * sc + sh + xa.y;
  oa.z = bflo(zv.y) * sc + sh + xa.z;
  oa.w = bfhi(zv.y) * sc + sh + xa.w;
  ob.x = bflo(zv.z) * sc + sh + xb.x;
  ob.y = bfhi(zv.z) * sc + sh + xb.y;
  ob.z = bflo(zv.w) * sc + sh + xb.z;
  ob.w = bfhi(zv.w) * sc + sh + xb.w;
  *(float4*)(out + flat) = oa;
  *(float4*)(out + flat + 4) = ob;
}

extern "C" void kernel_launch(void* const* d_in, const int* in_sizes, int n_in,
                              void* d_out, int out_size, void* d_ws, size_t ws_size,
                              hipStream_t stream) {
  (void)in_sizes; (void)n_in; (void)out_size; (void)ws_size;
  const float* x = (const float*)d_in[0];
  const float* Wt = (const float*)d_in[1];
  const float* bt = (const float*)d_in[2];
  const float* Wp = (const float*)d_in[3];
  const float* bp = (const float*)d_in[4];
  const float* Wg = (const float*)d_in[5];
  const float* bg = (const float*)d_in[6];
  const float* Wz = (const float*)d_in[7];
  const float* bz = (const float*)d_in[8];
  const float* gamma = (const float*)d_in[9];
  const float* beta = (const float*)d_in[10];

  unsigned char* Qb8 = (unsigned char*)d_ws;         // 2 MB (fp8)
  unsigned char* Kb8 = Qb8 + 2097152;                // 2 MB
  unsigned char* Vtb8 = Kb8 + 2097152;               // 2 MB
  unsigned short* Ytp = (unsigned short*)(Vtb8 + 2097152);  // 16 MB bf16 partials
  float* denp = (float*)(Ytp + 8388608);             // 256 KB
  float* Zr = denp + 65536;                          // 16 MB region (Zb uses 8 MB)
  float* Scale = Zr + 4194304;                       // 1 KB
  float* Shift = Scale + 256;

  // liveness aliases:
  unsigned short* Zb = (unsigned short*)Zr;          // bf16 Z
  unsigned short* xT = (unsigned short*)Zr;          // dead before zbn writes Zb
  unsigned short* Wb = (unsigned short*)denp;        // 192KB, dead before attn writes denp
  float* S1p = (float*)Qb8;                          // used after attn (Qb8 dead)
  float* S2p = S1p + 65536;

  prep_kernel<<<dim3(80, 4), 256, 0, stream>>>(x, Wt, Wp, Wg, xT, Wb);
  proj_kernel<<<dim3(64, 4, 3), 256, 0, stream>>>(xT, Wb, bt, bp, bg, Qb8, Kb8, Vtb8);
  attn_kernel<<<dim3(32, 4, 4), 256, 0, stream>>>(Qb8, Kb8, Vtb8, Ytp, denp);
  zbn_kernel<<<dim3(64, 4, 4), 256, 0, stream>>>(Ytp, denp, Wz, bz, Zb, S1p, S2p);
  bnfin_kernel<<<256, 256, 0, stream>>>(S1p, S2p, gamma, beta, Scale, Shift);
  out_kernel<<<2048, 256, 0, stream>>>(Zb, x, Scale, Shift, (float*)d_out);
}